// Round 8
// baseline (83.611 us; speedup 1.0000x reference)
//
#include <hip/hip_runtime.h>
#include <hip/hip_bf16.h>

// LocationHistoryEncoder: B=256, L=512, N=50000
//   recency[b,n] = max_t { rw^(L-1-t) * valid[b,t] : loc[b,t]==n } (baseline 0)
//   freq[b,n]    = sum_t { valid[b,t] : loc[b,t]==n }
//   out[b,n]     = recency + fw * freq / max(row_max(freq), 1)
//
// R3/R5 measured ~28us: fill+scatter two-phase with an exactly-resident
// lockstep grid -> fill drain serializes with hash, scatter re-touches
// evicted lines (write-allocate). R6..R8: SINGLE-PASS output. Build LDS
// hash (freq + extremal timesteps) + a 50000-bit presence bitmap,
// precompute each present location's final value, then stream the segment
// writing every element exactly once: broadcast bitmap word -> 4-bit
// nibble per float4; nib==0 (~99%) stores zeros, else hash-probe for the
// value. Nontemporal dwordx4 stores (output is never re-read).

constexpr int kB    = 256;
constexpr int kL    = 512;
constexpr int kN    = 50000;
constexpr int kSegs = 4;                 // blocks per row
constexpr int kSegN = kN / kSegs;        // 12500 floats (50000B, 16B-aligned)
constexpr int kH    = 1024;              // hash slots (pow2, ~2x distinct locs)
constexpr int kBMW  = (kN + 31) / 32;    // bitmap words = 1563

typedef float floatx4 __attribute__((ext_vector_type(4)));

__device__ __forceinline__ int hash_loc(int loc) {
    return (int)(((unsigned)loc * 2654435761u) >> 16) & (kH - 1);
}

__global__ __launch_bounds__(kL, 8) void loc_hist_enc_kernel(
    const int* __restrict__ loc_seq,
    const int* __restrict__ mask,
    const float* __restrict__ rw_p,
    const float* __restrict__ fw_p,
    float* __restrict__ out)
{
    const int b   = blockIdx.x >> 2;     // row
    const int seg = blockIdx.x & 3;      // quarter of the row we own
    const int t   = threadIdx.x;         // == timestep; blockDim.x == kL

    __shared__ int      h_key[kH];       // -1 = empty
    __shared__ int      h_cnt[kH];
    __shared__ int      h_tmin[kH];
    __shared__ int      h_tmax[kH];
    __shared__ float    h_val[kH];       // final out value per present loc
    __shared__ unsigned s_bm[kBMW];      // presence bitmap over [0, kN)
    __shared__ float    s_pw[kL];        // rw^k
    __shared__ float    s_red[kL / 64];

    const float rw = rw_p[0];
    const float fw = fw_p[0];
    const int   loc = loc_seq[b * kL + t];
    const int   v   = mask[b * kL + t];  // 0 or 1

    // ---- Phase 0: init hash, bitmap, power table.
    #pragma unroll
    for (int s = t; s < kH; s += kL) {
        h_key[s]  = -1;
        h_cnt[s]  = 0;
        h_tmin[s] = 0x7fffffff;
        h_tmax[s] = -1;
    }
    for (int s = t; s < kBMW; s += kL) s_bm[s] = 0u;
    s_pw[t] = powf(rw, (float)t);
    __syncthreads();

    // ---- Phase 1: O(L) dedup into hash + presence bitmap.
    if (v) {
        int s = hash_loc(loc);
        while (true) {
            const int k = atomicCAS(&h_key[s], -1, loc);
            if (k == -1 || k == loc) break;
            s = (s + 1) & (kH - 1);
        }
        atomicAdd(&h_cnt[s], 1);
        atomicMin(&h_tmin[s], t);
        atomicMax(&h_tmax[s], t);
        atomicOr(&s_bm[loc >> 5], 1u << (loc & 31));
    }
    __syncthreads();

    // ---- Phase 2: row-wide max frequency (empty slots hold 0).
    float mf = fmaxf((float)h_cnt[t], (float)h_cnt[t + kL]);
    #pragma unroll
    for (int off = 32; off >= 1; off >>= 1)
        mf = fmaxf(mf, __shfl_xor(mf, off));
    if ((t & 63) == 0) s_red[t >> 6] = mf;
    __syncthreads();
    float m = 1.0f;                      // reference clamps max_freq >= 1
    #pragma unroll
    for (int w = 0; w < kL / 64; ++w) m = fmaxf(m, s_red[w]);

    // ---- Phase 3: precompute final value per occupied slot.
    // rec = max over valid t of rw^(L-1-t): monotone -> extremal occurrence.
    #pragma unroll
    for (int s = t; s < kH; s += kL) {
        if (h_key[s] >= 0) {
            const float rec = fmaxf(s_pw[kL - 1 - h_tmax[s]],
                                    s_pw[kL - 1 - h_tmin[s]]);
            h_val[s] = rec + fw * ((float)h_cnt[s] / m);
        }
    }
    __syncthreads();

    // ---- Phase 4: single-pass stream of OUR segment; every element
    // written exactly once. One broadcast bitmap word per float4.
    floatx4* __restrict__ oseg =
        reinterpret_cast<floatx4*>(out + (size_t)b * kN + (size_t)seg * kSegN);
    const int n0base = seg * kSegN;
    for (int i = t; i < kSegN / 4; i += kL) {
        const int      n0  = n0base + i * 4;
        const unsigned w   = s_bm[n0 >> 5];
        const unsigned nib = (w >> (n0 & 31)) & 0xFu;   // n0 % 4 == 0
        floatx4 o = {0.f, 0.f, 0.f, 0.f};
        if (nib) {                                       // rare (~1%)
            #pragma unroll
            for (int e = 0; e < 4; ++e) {
                if (nib & (1u << e)) {
                    const int n = n0 + e;
                    int s = hash_loc(n);
                    while (h_key[s] != n) s = (s + 1) & (kH - 1);
                    o[e] = h_val[s];
                }
            }
        }
        __builtin_nontemporal_store(o, &oseg[i]);
    }
}

extern "C" void kernel_launch(void* const* d_in, const int* in_sizes, int n_in,
                              void* d_out, int out_size, void* d_ws, size_t ws_size,
                              hipStream_t stream) {
    const int*   loc_seq = (const int*)d_in[0];
    const int*   mask    = (const int*)d_in[1];
    const float* rw      = (const float*)d_in[2];
    const float* fw      = (const float*)d_in[3];
    // d_in[4] = num_locations (compile-time constant kN)
    float* out = (float*)d_out;

    loc_hist_enc_kernel<<<kB * kSegs, kL, 0, stream>>>(loc_seq, mask, rw, fw, out);
}

// Round 9
// 80.926 us; speedup vs baseline: 1.0332x; 1.0332x over previous
//
#include <hip/hip_runtime.h>
#include <hip/hip_bf16.h>

// LocationHistoryEncoder: B=256, L=512, N=50000
//   recency[b,n] = max_t { rw^(L-1-t) * valid[b,t] : loc[b,t]==n } (baseline 0)
//   freq[b,n]    = sum_t { valid[b,t] : loc[b,t]==n }
//   out[b,n]     = recency + fw * freq / max(row_max(freq), 1)
//
// Cross-round fit (R2=91.7/R3=79.7/R5=80.6/R8=83.6 total):  per-replay
// fixed cost ~70us (268MB ws-poison 44us + 51MB out-poison 9us + graph
// node overhead) => kernel has been ~10-13us since R3, near the 8.5us
// write roofline for 51.2MB. R8's +3us regression = nontemporal 16B
// stores bypassing L2 write-combining. R9: single-pass (every element
// written exactly once), REGULAR dwordx4 stores, relaxed launch bounds.
// Structure: per-row LDS hash (freq + extremal timesteps; rec=rw^(L-1-t)
// is monotone in t so the scatter-max is at an extremal occurrence) +
// presence bitmap; stream own 1/4-row segment, bitmap nibble per float4,
// ~1% present elements resolved by hash probe of precomputed h_val.

constexpr int kB    = 256;
constexpr int kL    = 512;
constexpr int kN    = 50000;
constexpr int kSegs = 4;                 // blocks per row
constexpr int kSegN = kN / kSegs;        // 12500 floats (50000B, 16B-aligned)
constexpr int kH    = 1024;              // hash slots (pow2, ~2x distinct locs)
constexpr int kBMW  = (kN + 31) / 32;    // bitmap words = 1563

__device__ __forceinline__ int hash_loc(int loc) {
    return (int)(((unsigned)loc * 2654435761u) >> 16) & (kH - 1);
}

__global__ __launch_bounds__(kL, 4) void loc_hist_enc_kernel(
    const int* __restrict__ loc_seq,
    const int* __restrict__ mask,
    const float* __restrict__ rw_p,
    const float* __restrict__ fw_p,
    float* __restrict__ out)
{
    const int b   = blockIdx.x >> 2;     // row
    const int seg = blockIdx.x & 3;      // quarter of the row we own
    const int t   = threadIdx.x;         // == timestep; blockDim.x == kL

    __shared__ int      h_key[kH];       // -1 = empty
    __shared__ int      h_cnt[kH];
    __shared__ int      h_tmin[kH];
    __shared__ int      h_tmax[kH];
    __shared__ float    h_val[kH];       // final out value per present loc
    __shared__ unsigned s_bm[kBMW];      // presence bitmap over [0, kN)
    __shared__ float    s_pw[kL];        // rw^k
    __shared__ float    s_red[kL / 64];

    const float rw = rw_p[0];
    const float fw = fw_p[0];
    const int   loc = loc_seq[b * kL + t];
    const int   v   = mask[b * kL + t];  // 0 or 1

    // ---- Phase 0: init hash, bitmap, power table.
    #pragma unroll
    for (int s = t; s < kH; s += kL) {
        h_key[s]  = -1;
        h_cnt[s]  = 0;
        h_tmin[s] = 0x7fffffff;
        h_tmax[s] = -1;
    }
    for (int s = t; s < kBMW; s += kL) s_bm[s] = 0u;
    s_pw[t] = powf(rw, (float)t);
    __syncthreads();

    // ---- Phase 1: O(L) dedup into hash + presence bitmap.
    if (v) {
        int s = hash_loc(loc);
        while (true) {
            const int k = atomicCAS(&h_key[s], -1, loc);
            if (k == -1 || k == loc) break;
            s = (s + 1) & (kH - 1);
        }
        atomicAdd(&h_cnt[s], 1);
        atomicMin(&h_tmin[s], t);
        atomicMax(&h_tmax[s], t);
        atomicOr(&s_bm[loc >> 5], 1u << (loc & 31));
    }
    __syncthreads();

    // ---- Phase 2: row-wide max frequency (empty slots hold 0).
    float mf = fmaxf((float)h_cnt[t], (float)h_cnt[t + kL]);
    #pragma unroll
    for (int off = 32; off >= 1; off >>= 1)
        mf = fmaxf(mf, __shfl_xor(mf, off));
    if ((t & 63) == 0) s_red[t >> 6] = mf;
    __syncthreads();
    float m = 1.0f;                      // reference clamps max_freq >= 1
    #pragma unroll
    for (int w = 0; w < kL / 64; ++w) m = fmaxf(m, s_red[w]);

    // ---- Phase 3: precompute final value per occupied slot.
    // rec = max over valid t of rw^(L-1-t): monotone -> extremal occurrence.
    #pragma unroll
    for (int s = t; s < kH; s += kL) {
        if (h_key[s] >= 0) {
            const float rec = fmaxf(s_pw[kL - 1 - h_tmax[s]],
                                    s_pw[kL - 1 - h_tmin[s]]);
            h_val[s] = rec + fw * ((float)h_cnt[s] / m);
        }
    }
    __syncthreads();

    // ---- Phase 4: single-pass stream of OUR segment; every element
    // written exactly once via regular dwordx4 (L2 write-combining).
    float4* __restrict__ oseg =
        reinterpret_cast<float4*>(out + (size_t)b * kN + (size_t)seg * kSegN);
    const int n0base = seg * kSegN;
    for (int i = t; i < kSegN / 4; i += kL) {
        const int      n0  = n0base + i * 4;
        const unsigned w   = s_bm[n0 >> 5];
        const unsigned nib = (w >> (n0 & 31)) & 0xFu;   // n0 % 4 == 0
        float4 o = make_float4(0.f, 0.f, 0.f, 0.f);
        if (nib) {                                       // rare (~1%)
            #pragma unroll
            for (int e = 0; e < 4; ++e) {
                if (nib & (1u << e)) {
                    const int n = n0 + e;
                    int s = hash_loc(n);
                    while (h_key[s] != n) s = (s + 1) & (kH - 1);
                    (&o.x)[e] = h_val[s];
                }
            }
        }
        oseg[i] = o;
    }
}

extern "C" void kernel_launch(void* const* d_in, const int* in_sizes, int n_in,
                              void* d_out, int out_size, void* d_ws, size_t ws_size,
                              hipStream_t stream) {
    const int*   loc_seq = (const int*)d_in[0];
    const int*   mask    = (const int*)d_in[1];
    const float* rw      = (const float*)d_in[2];
    const float* fw      = (const float*)d_in[3];
    // d_in[4] = num_locations (compile-time constant kN)
    float* out = (float*)d_out;

    loc_hist_enc_kernel<<<kB * kSegs, kL, 0, stream>>>(loc_seq, mask, rw, fw, out);
}